// Round 6
// baseline (344.555 us; speedup 1.0000x reference)
//
#include <hip/hip_runtime.h>
#include <hip/hip_bf16.h>

#define NN 10000
#define NE 100000

typedef __attribute__((ext_vector_type(8))) short short8v;
typedef __attribute__((ext_vector_type(4))) float float4v;

__device__ __forceinline__ unsigned int enc_f(float f) {
  unsigned int u = __float_as_uint(f);
  return (u & 0x80000000u) ? ~u : (u | 0x80000000u);
}
__device__ __forceinline__ float dec_f(unsigned int u) {
  return __uint_as_float((u & 0x80000000u) ? (u & 0x7fffffffu) : ~u);
}
__device__ __forceinline__ float silu_f(float x) {
  return x / (1.0f + __expf(-x));
}
// fp32 -> bf16 hi/lo split: x ~= hi + lo with ~2^-16 relative error.
__device__ __forceinline__ void f32_hilo(float x, short& h, short& l) {
  __hip_bfloat16 bh = __float2bfloat16(x);
  float r = x - __bfloat162float(bh);
  __hip_bfloat16 bl = __float2bfloat16(r);
  h = __builtin_bit_cast(short, bh);
  l = __builtin_bit_cast(short, bl);
}
#define MFMA16(a, b, c) __builtin_amdgcn_mfma_f32_16x16x32_bf16(a, b, c, 0, 0, 0)

// ---------------- prep: Q + MFMA weight fragment packs.
// Pack layout per GEMM: idx = ((nt*KF + kf)*64 + lane)*8 + j
//   holds W[k][n] with k = kf*32 + 8*(lane>>4) + j, n = nt*16 + (lane&15).
// A and B use the SAME k bijection -> result invariant to the HW's actual k map.
// Wp4 packs W_msg TRANSPOSED: B[k=m][n=c2] = W_msg[c2*128 + m]  (t = u @ W_msg^T).
__global__ void prep_kernel(const float* __restrict__ W_msg, const float* __restrict__ W_val,
                            const float* __restrict__ W_out, const float* __restrict__ W_rbf,
                            const float* __restrict__ W_gate,
                            float* __restrict__ Q,
                            short* __restrict__ Wp1h, short* __restrict__ Wp1l,
                            short* __restrict__ Wp2h, short* __restrict__ Wp2l,
                            short* __restrict__ Wp3h, short* __restrict__ Wp3l,
                            short* __restrict__ Wp4h, short* __restrict__ Wp4l) {
  int i = blockIdx.x * blockDim.x + threadIdx.x;  // grid = 192*256 = 49152
  if (i < 1024) {
    int c = i >> 3, h = i & 7;
    float s = 0.0f;
#pragma unroll
    for (int dv = 0; dv < 16; ++dv)
      s += W_val[c * 128 + h * 16 + dv] * W_out[h * 16 + dv];
    Q[c * 8 + h] = s;
  }
  const float* W; short* ph; short* pl; int KF, Nw, local; bool tr = false;
  if (i < 8192)       { W = W_rbf;  ph = Wp1h; pl = Wp1l; KF = 4; Nw = 64;  local = i; }
  else if (i < 16384) { W = W_gate; ph = Wp2h; pl = Wp2l; KF = 2; Nw = 128; local = i - 8192; }
  else if (i < 32768) { W = W_msg;  ph = Wp3h; pl = Wp3l; KF = 4; Nw = 128; local = i - 16384; }
  else                { W = W_msg;  ph = Wp4h; pl = Wp4l; KF = 4; Nw = 128; local = i - 32768; tr = true; }
  int tile = local >> 9;           // nt*KF + kf
  int ln = (local >> 3) & 63;
  int j = local & 7;
  int nt = tile / KF, kf = tile % KF;
  int k = kf * 32 + 8 * (ln >> 4) + j;
  int n = nt * 16 + (ln & 15);
  float w = tr ? W[n * 128 + k] : W[k * Nw + n];
  short h, lo;
  f32_hilo(w, h, lo);
  ph[local] = h;
  pl[local] = lo;
}

// ---------------- G1: one wave per edge; xc[e][0:64]=x_s0, [64:128]=x_t0.
// All 27 loads in flight at once; 100K waves give the TLP to hide L2/L3 latency.
__global__ __launch_bounds__(256) void gather1_kernel(
    const float* __restrict__ nb, const int* __restrict__ ei,
    const float* __restrict__ wig, float* __restrict__ xc) {
  const int lane = threadIdx.x & 63;
  const int e = blockIdx.x * 4 + (threadIdx.x >> 6);  // NE % 4 == 0
  int se = ei[e], de = ei[NE + e];
  const float* __restrict__ pw = wig + (size_t)e * 81;
  const float* __restrict__ ps = nb + (size_t)se * 576 + lane;
  const float* __restrict__ pt = nb + (size_t)de * 576 + lane;
  float vs[9], vt[9], wj[9];
#pragma unroll
  for (int j = 0; j < 9; ++j) {
    vs[j] = ps[j * 64];
    vt[j] = pt[j * 64];
    wj[j] = pw[j];
  }
  float xs = 0.0f, xt = 0.0f;
#pragma unroll
  for (int j = 0; j < 9; ++j) { xs += wj[j] * vs[j]; xt += wj[j] * vt[j]; }
  xc[(size_t)e * 128 + lane] = xs;
  xc[(size_t)e * 128 + 64 + lane] = xt;
}

// ---------------- P1 (MFMA): gate (bf16 ws), logits, segment-max.
// No gather: A3 frags load straight from xc_ws in fragment order.
__global__ __launch_bounds__(256, 3) void pass1_kernel(
    const int* __restrict__ zn, const float* __restrict__ dist,
    const int* __restrict__ ei, const float* __restrict__ aemb,
    const float* __restrict__ alpha, const float* __restrict__ xc,
    const short* __restrict__ Wp1h, const short* __restrict__ Wp1l,
    const short* __restrict__ Wp2h, const short* __restrict__ Wp2l,
    const short* __restrict__ Wp3h, const short* __restrict__ Wp3l,
    float* __restrict__ logits, unsigned int* __restrict__ m_enc,
    __hip_bfloat16* __restrict__ gate_ws) {
  __shared__ __attribute__((aligned(16))) float es_s[4][16][68];
  const int tid = threadIdx.x;
  const int lane = tid & 63;
  const int wid = tid >> 6;
  const int g = lane >> 4;
  const int col = lane & 15;
  const int e0 = (blockIdx.x * 4 + wid) * 16;

  // preload the wave's 32 edge indices: lanes 0..15 = src, 16..31 = dst
  int l16 = lane & 15;
  int ecl16 = (e0 + l16 < NE) ? e0 + l16 : NE - 1;
  int idx_v = 0;
  if (lane < 32) idx_v = ei[(lane < 16 ? 0 : NE) + ecl16];

  int ecol = e0 + col; if (ecol >= NE) ecol = NE - 1;
  const float d = dist[ecol];

  // ---- A3 raw loads from xc (issued early; L3-resident) ----
  const float* __restrict__ xr = xc + (size_t)ecol * 128;
  float4v xv[4][2];
#pragma unroll
  for (int kf = 0; kf < 4; ++kf) {
    xv[kf][0] = *(const float4v*)(xr + kf * 32 + 8 * g);
    xv[kf][1] = *(const float4v*)(xr + kf * 32 + 8 * g + 4);
  }

  // ---- rbf A-frags (direct in fragment layout) ----
  short8v a1h[4], a1l[4];
#pragma unroll
  for (int kf = 0; kf < 4; ++kf) {
#pragma unroll
    for (int j = 0; j < 8; ++j) {
      int k = kf * 32 + 8 * g + j;
      float t = d - (float)k * (1.0f / 127.0f);
      float v = __expf(-8192.0f * t * t);
      short h, lo; f32_hilo(v, h, lo);
      a1h[kf][j] = h; a1l[kf][j] = lo;
    }
  }

  const float4v z4 = {0.0f, 0.0f, 0.0f, 0.0f};

  // ---- GEMM1: es_raw(16x64) = rbf(16x128) @ W_rbf ----
  float4v acc1[4];
#pragma unroll
  for (int nt = 0; nt < 4; ++nt) {
    float4v a = z4;
#pragma unroll
    for (int kf = 0; kf < 4; ++kf) {
      short8v bh = *(const short8v*)(Wp1h + ((nt * 4 + kf) * 64 + lane) * 8);
      short8v bl = *(const short8v*)(Wp1l + ((nt * 4 + kf) * 64 + lane) * 8);
      a = MFMA16(a1h[kf], bh, a);
      a = MFMA16(a1h[kf], bl, a);
      a = MFMA16(a1l[kf], bh, a);
    }
    acc1[nt] = a;
  }

  // ---- bias + silu -> es rows (per-wave in-order LDS; no barrier needed) ----
  // __shfl (ds_bpermute) handles the divergent 4*g+r source lane; readlane does NOT.
  int dn_r[4];
#pragma unroll
  for (int r = 0; r < 4; ++r) {
    int sn = __shfl(idx_v, 4 * g + r);
    dn_r[r] = __shfl(idx_v, 16 + 4 * g + r);
    int zs = zn[sn], zd = zn[dn_r[r]];
#pragma unroll
    for (int nt = 0; nt < 4; ++nt) {
      float b = aemb[zs * 64 + nt * 16 + col] + aemb[zd * 64 + nt * 16 + col];
      es_s[wid][4 * g + r][nt * 16 + col] = silu_f(acc1[nt][r] + b);
    }
  }

  // ---- GEMM2 A-frags from es rows ----
  short8v a2h[2], a2l[2];
#pragma unroll
  for (int kf = 0; kf < 2; ++kf) {
    const float* p = &es_s[wid][col][kf * 32 + 8 * g];
    float4v v0 = *(const float4v*)p;
    float4v v1 = *(const float4v*)(p + 4);
#pragma unroll
    for (int j = 0; j < 4; ++j) {
      short h, lo;
      f32_hilo(v0[j], h, lo); a2h[kf][j] = h;     a2l[kf][j] = lo;
      f32_hilo(v1[j], h, lo); a2h[kf][4 + j] = h; a2l[kf][4 + j] = lo;
    }
  }

  // ---- GEMM2: gate = silu(es @ W_gate), store bf16 ----
  float gate_r[8][4];
#pragma unroll
  for (int nt = 0; nt < 8; ++nt) {
    float4v a = z4;
#pragma unroll
    for (int kf = 0; kf < 2; ++kf) {
      short8v bh = *(const short8v*)(Wp2h + ((nt * 2 + kf) * 64 + lane) * 8);
      short8v bl = *(const short8v*)(Wp2l + ((nt * 2 + kf) * 64 + lane) * 8);
      a = MFMA16(a2h[kf], bh, a);
      a = MFMA16(a2h[kf], bl, a);
      a = MFMA16(a2l[kf], bh, a);
    }
#pragma unroll
    for (int r = 0; r < 4; ++r) {
      float gv = silu_f(a[r]);
      gate_r[nt][r] = gv;
      int er = e0 + 4 * g + r;
      if (er < NE)
        gate_ws[(size_t)er * 128 + nt * 16 + col] = __float2bfloat16(gv);
    }
  }

  // ---- A3 frag pack from xv ----
  short8v a3h[4], a3l[4];
#pragma unroll
  for (int kf = 0; kf < 4; ++kf) {
#pragma unroll
    for (int j = 0; j < 4; ++j) {
      short h, lo;
      f32_hilo(xv[kf][0][j], h, lo); a3h[kf][j] = h;     a3l[kf][j] = lo;
      f32_hilo(xv[kf][1][j], h, lo); a3h[kf][4 + j] = h; a3l[kf][4 + j] = lo;
    }
  }

  // ---- GEMM3: msg0 = xcat @ W_msg ; epilogue: logits + segment-max ----
#pragma unroll
  for (int nt = 0; nt < 8; ++nt) {
    float4v a = z4;
#pragma unroll
    for (int kf = 0; kf < 4; ++kf) {
      short8v bh = *(const short8v*)(Wp3h + ((nt * 4 + kf) * 64 + lane) * 8);
      short8v bl = *(const short8v*)(Wp3l + ((nt * 4 + kf) * 64 + lane) * 8);
      a = MFMA16(a3h[kf], bh, a);
      a = MFMA16(a3h[kf], bl, a);
      a = MFMA16(a3l[kf], bh, a);
    }
    float al = alpha[nt * 16 + col];
#pragma unroll
    for (int r = 0; r < 4; ++r) {
      float v = a[r] * gate_r[nt][r];
      v = v > 0.0f ? v : 0.2f * v;
      v *= al;
#pragma unroll
      for (int off = 1; off < 16; off <<= 1) v += __shfl_xor(v, off);
      int er = e0 + 4 * g + r;
      if (col == 0 && er < NE) {
        logits[(size_t)er * 8 + nt] = v;
        atomicMax(&m_enc[dn_r[r] * 8 + nt], enc_f(v));
      }
    }
  }
}

// ---------------- pass2: den[n,h] += exp(logit - m[n,h])  [unchanged]
__global__ void pass2_kernel(const float* __restrict__ logits,
                             const int* __restrict__ ei,
                             const unsigned int* __restrict__ m_enc,
                             float* __restrict__ den) {
  int i = blockIdx.x * blockDim.x + threadIdx.x;
  if (i >= NE * 8) return;
  int e = i >> 3, h = i & 7;
  int dn = ei[NE + e];
  float mm = dec_f(m_enc[dn * 8 + h]);
  atomicAdd(&den[dn * 8 + h], __expf(logits[i] - mm));
}

// ---------------- P3a (MFMA): attn -> u -> t = u @ W_msg^T -> t_ws
__global__ __launch_bounds__(256, 3) void pass3a_kernel(
    const int* __restrict__ ei, const float* __restrict__ logits,
    const unsigned int* __restrict__ m_enc, const float* __restrict__ den,
    const __hip_bfloat16* __restrict__ gate_ws, const float* __restrict__ Q,
    const short* __restrict__ Wp4h, const short* __restrict__ Wp4l,
    float* __restrict__ t_ws) {
  __shared__ __attribute__((aligned(16))) float attn_s[4][16][8];
  __shared__ __attribute__((aligned(16))) float x_s[4][16][132];  // u
  const int tid = threadIdx.x;
  const int lane = tid & 63;
  const int wid = tid >> 6;
  const int g = lane >> 4;
  const int col = lane & 15;
  const int e0 = (blockIdx.x * 4 + wid) * 16;

  // ---- phase A: attn for 16 edges x 8 heads ----
#pragma unroll
  for (int half = 0; half < 2; ++half) {
    int i = half * 64 + lane;
    int e = i >> 3, h = i & 7;
    int ec = e0 + e; if (ec >= NE) ec = NE - 1;
    int dn = ei[NE + ec];
    float l = logits[(size_t)ec * 8 + h];
    float mm = dec_f(m_enc[dn * 8 + h]);
    float dv = den[dn * 8 + h];
    attn_s[wid][e][h] = __expf(l - mm) / (dv + 1e-9f);
  }

  // ---- phase B: u[e, m] for m = 2*lane, 2*lane+1 (paired bf16 gate load) ----
  float q0[8], q1[8];
#pragma unroll
  for (int h = 0; h < 8; ++h) {
    q0[h] = Q[(2 * lane) * 8 + h];
    q1[h] = Q[(2 * lane + 1) * 8 + h];
  }
#pragma unroll 4
  for (int e = 0; e < 16; ++e) {
    int ec = e0 + e; if (ec >= NE) ec = NE - 1;
    float4v a0 = *(const float4v*)&attn_s[wid][e][0];
    float4v a1 = *(const float4v*)&attn_s[wid][e][4];
    float wv0 = 0.0f, wv1 = 0.0f;
#pragma unroll
    for (int h = 0; h < 4; ++h) {
      wv0 += q0[h] * a0[h] + q0[4 + h] * a1[h];
      wv1 += q1[h] * a0[h] + q1[4 + h] * a1[h];
    }
    unsigned int gp = *(const unsigned int*)(gate_ws + (size_t)ec * 128 + 2 * lane);
    float gg0 = __uint_as_float((gp & 0xffffu) << 16);
    float gg1 = __uint_as_float((gp & 0xffff0000u));
    float2 uu; uu.x = gg0 * wv0; uu.y = gg1 * wv1;
    *(float2*)&x_s[wid][e][2 * lane] = uu;
  }

  // ---- phase C: A-frags from u, T = U @ Wp4 (96 MFMA), t -> global ----
  short8v ah[4], al[4];
#pragma unroll
  for (int kf = 0; kf < 4; ++kf) {
    const float* p = &x_s[wid][col][kf * 32 + 8 * g];
    float4v v0 = *(const float4v*)p;
    float4v v1 = *(const float4v*)(p + 4);
#pragma unroll
    for (int j = 0; j < 4; ++j) {
      short h, lo;
      f32_hilo(v0[j], h, lo); ah[kf][j] = h;     al[kf][j] = lo;
      f32_hilo(v1[j], h, lo); ah[kf][4 + j] = h; al[kf][4 + j] = lo;
    }
  }
  const float4v z4 = {0.0f, 0.0f, 0.0f, 0.0f};
#pragma unroll
  for (int nt = 0; nt < 8; ++nt) {
    float4v a = z4;
#pragma unroll
    for (int kf = 0; kf < 4; ++kf) {
      short8v bh = *(const short8v*)(Wp4h + ((nt * 4 + kf) * 64 + lane) * 8);
      short8v bl = *(const short8v*)(Wp4l + ((nt * 4 + kf) * 64 + lane) * 8);
      a = MFMA16(ah[kf], bh, a);
      a = MFMA16(ah[kf], bl, a);
      a = MFMA16(al[kf], bh, a);
    }
#pragma unroll
    for (int r = 0; r < 4; ++r) {
      int er = e0 + 4 * g + r;
      if (er < NE)
        t_ws[(size_t)er * 128 + nt * 16 + col] = a[r];
    }
  }
}

// ---------------- P3b: one wave per edge; gather + 9 dots + wigner epilogue
__global__ __launch_bounds__(256) void pass3b_kernel(
    const float* __restrict__ nb, const int* __restrict__ ei,
    const float* __restrict__ wig, const float* __restrict__ t_ws,
    float* __restrict__ out) {
  const int lane = threadIdx.x & 63;
  const int e = blockIdx.x * 4 + (threadIdx.x >> 6);  // NE % 4 == 0
  int se = ei[e], de = ei[NE + e];
  float t0 = t_ws[(size_t)e * 128 + lane];
  float t1 = t_ws[(size_t)e * 128 + 64 + lane];
  const float* __restrict__ ps = nb + (size_t)se * 576 + lane;
  const float* __restrict__ pt = nb + (size_t)de * 576 + lane;
  float p[9];
#pragma unroll
  for (int j = 0; j < 9; ++j)
    p[j] = ps[j * 64] * t0 + pt[j * 64] * t1;
  // full 64-lane butterfly; afterwards every lane holds d[j]
#pragma unroll
  for (int off = 1; off < 64; off <<= 1)
#pragma unroll
    for (int j = 0; j < 9; ++j) p[j] += __shfl_xor(p[j], off);

  const float* __restrict__ we = wig + (size_t)e * 81;
  int ls = lane < 9 ? lane : 8;
  float s_l = 0.0f;
#pragma unroll
  for (int jp = 0; jp < 9; ++jp) s_l += we[ls * 9 + jp] * p[jp];
  int lc = (lane >= 1 && lane <= 3) ? lane : 1;
  float f = 0.0f;
#pragma unroll
  for (int j = 0; j < 9; ++j)
    f += __shfl(s_l, j) * we[j * 9 + lc];
  if (lane >= 1 && lane <= 3)
    atomicAdd(&out[de * 3 + (lane - 1)], f);
}

extern "C" void kernel_launch(void* const* d_in, const int* in_sizes, int n_in,
                              void* d_out, int out_size, void* d_ws, size_t ws_size,
                              hipStream_t stream) {
  const float* nb = (const float*)d_in[0];
  const int* zn = (const int*)d_in[1];
  const float* dist = (const float*)d_in[2];
  const int* ei = (const int*)d_in[3];
  const float* wig = (const float*)d_in[4];
  const float* aemb = (const float*)d_in[5];
  const float* W_rbf = (const float*)d_in[6];
  const float* W_gate = (const float*)d_in[7];
  const float* W_msg = (const float*)d_in[8];
  const float* alpha = (const float*)d_in[9];
  const float* W_val = (const float*)d_in[10];
  const float* W_out = (const float*)d_in[11];
  float* out = (float*)d_out;

  // workspace layout (~81 MB)
  char* p = (char*)d_ws;
  float* Q = (float*)p;                   p += 1024 * 4;
  unsigned int* m_enc = (unsigned int*)p; p += (size_t)NN * 8 * 4;
  float* den = (float*)p;                 p += (size_t)NN * 8 * 4;
  float* logits = (float*)p;              p += (size_t)NE * 8 * 4;
  __hip_bfloat16* gate_ws = (__hip_bfloat16*)p; p += (size_t)NE * 128 * 2;
  short* Wp1h = (short*)p; p += 8192 * 2;
  short* Wp1l = (short*)p; p += 8192 * 2;
  short* Wp2h = (short*)p; p += 8192 * 2;
  short* Wp2l = (short*)p; p += 8192 * 2;
  short* Wp3h = (short*)p; p += 16384 * 2;
  short* Wp3l = (short*)p; p += 16384 * 2;
  short* Wp4h = (short*)p; p += 16384 * 2;
  short* Wp4l = (short*)p; p += 16384 * 2;
  float* xc_ws = (float*)p;               p += (size_t)NE * 128 * 4;
  float* t_ws = xc_ws;  // aliased: xc consumed by P1 before P3a writes t

  hipMemsetAsync(d_out, 0, (size_t)NN * 3 * 4, stream);
  hipMemsetAsync(m_enc, 0, (size_t)NN * 8 * 4, stream);
  hipMemsetAsync(den, 0, (size_t)NN * 8 * 4, stream);

  prep_kernel<<<192, 256, 0, stream>>>(W_msg, W_val, W_out, W_rbf, W_gate, Q,
                                       Wp1h, Wp1l, Wp2h, Wp2l, Wp3h, Wp3l, Wp4h, Wp4l);
  gather1_kernel<<<NE / 4, 256, 0, stream>>>(nb, ei, wig, xc_ws);
  pass1_kernel<<<(NE + 63) / 64, 256, 0, stream>>>(zn, dist, ei, aemb, alpha, xc_ws,
                                                   Wp1h, Wp1l, Wp2h, Wp2l, Wp3h, Wp3l,
                                                   logits, m_enc, gate_ws);
  pass2_kernel<<<(NE * 8 + 255) / 256, 256, 0, stream>>>(logits, ei, m_enc, den);
  pass3a_kernel<<<(NE + 63) / 64, 256, 0, stream>>>(ei, logits, m_enc, den,
                                                    gate_ws, Q, Wp4h, Wp4l, t_ws);
  pass3b_kernel<<<NE / 4, 256, 0, stream>>>(nb, ei, wig, t_ws, out);
}